// Round 8
// baseline (375.724 us; speedup 1.0000x reference)
//
#include <hip/hip_runtime.h>
#include <hip/hip_bf16.h>

// LSTM cell: B=16384, D=H=1024. out = (h_next, c_next) fp32, each 16384x1024.
// R8: 128M x (4g x 32N) tile, acc=64/lane -> ~3 blocks/CU (m97/m103 profile),
// R1's proven 2-barrier schedule + proven BK=64 XOR swizzle (0 conflicts).

#define MROWS 16384
#define NCOLS 1024
#define KTOT  2048

typedef __attribute__((ext_vector_type(8))) short bf16x8;
typedef __attribute__((ext_vector_type(4))) float f32x4;
typedef unsigned int u32;
typedef unsigned short u16;

__device__ __forceinline__ u16 f2bf(float f) {
  union { float f; u32 u; } v; v.f = f;
  u32 r = v.u + 0x7fffu + ((v.u >> 16) & 1u);   // RNE truncate f32->bf16
  return (u16)(r >> 16);
}

__device__ __forceinline__ bf16x8 pack8(float4 lo, float4 hi) {
  bf16x8 v;
  v[0] = (short)f2bf(lo.x); v[1] = (short)f2bf(lo.y);
  v[2] = (short)f2bf(lo.z); v[3] = (short)f2bf(lo.w);
  v[4] = (short)f2bf(hi.x); v[5] = (short)f2bf(hi.y);
  v[6] = (short)f2bf(hi.z); v[7] = (short)f2bf(hi.w);
  return v;
}

__device__ __forceinline__ float tanh_fast(float x) {
  float e = __expf(2.0f * x);
  return 1.0f - 2.0f / (e + 1.0f);
}

typedef __attribute__((address_space(1))) const u32 gas_u32;
typedef __attribute__((address_space(3))) u32 las_u32;

__device__ __forceinline__ void gl_lds16(const void* g, void* l) {
  __builtin_amdgcn_global_load_lds((gas_u32*)g, (las_u32*)l, 16, 0, 0);
}

// ---- merged conversion kernel (fast path) ----
// blocks 0..4095: A_bf16 [16384][2048] (cols 0..1023 = x, 1024..2047 = h)
// blocks 4096..5119: W_bf16 [gate][1024][2048], gate order i,f,c,o.
__global__ void __launch_bounds__(256) convAW(
    const float* __restrict__ x, const float* __restrict__ h,
    const float* __restrict__ wix, const float* __restrict__ wfx,
    const float* __restrict__ wcx, const float* __restrict__ wox,
    const float* __restrict__ wih, const float* __restrict__ wfh,
    const float* __restrict__ wch, const float* __restrict__ woh,
    u16* __restrict__ A, u16* __restrict__ W) {
  if (blockIdx.x < 4096u) {
    u32 t = blockIdx.x * 256u + threadIdx.x;
    #pragma unroll
    for (int i = 0; i < 4; ++i) {
      u32 chunk = t + (u32)i * 1048576u;
      u32 row = chunk >> 8;
      u32 cpos = (chunk & 255u) * 8u;
      const float* src = (cpos < 1024u) ? (x + (size_t)row * 1024 + cpos)
                                        : (h + (size_t)row * 1024 + (cpos - 1024u));
      float4 lo = *(const float4*)src;
      float4 hi = *(const float4*)(src + 4);
      *(bf16x8*)(A + (size_t)chunk * 8) = pack8(lo, hi);
    }
  } else {
    u32 t = (blockIdx.x - 4096u) * 256u + threadIdx.x;
    const float* WX[4] = {wix, wfx, wcx, wox};
    const float* WH[4] = {wih, wfh, wch, woh};
    #pragma unroll
    for (int g = 0; g < 4; ++g) {
      u32 n = t >> 8;
      u32 cpos = (t & 255u) * 8u;
      const float* src = (cpos < 1024u) ? (WX[g] + (size_t)n * 1024 + cpos)
                                        : (WH[g] + (size_t)n * 1024 + (cpos - 1024u));
      float4 lo = *(const float4*)src;
      float4 hi = *(const float4*)(src + 4);
      *(bf16x8*)(W + (size_t)g * 2097152 + (size_t)t * 8) = pack8(lo, hi);
    }
  }
}

// ---- fused 4-gate GEMM, 128x128-fused tile ----
// Block: 256 thr (4 waves 2x2). Tile 128(M) x 32(N/gate) x 4 gates, BK=64, 32 K-tiles.
// Wave: 64M x 64N-fused (16 cols x 4 gates) -> acc[4 g][4 mf] f32x4 = 64 regs.
// B fused row fr in [0,128): fi=fr>>4, gate=fi&3, half=fi>>2;
//   Wrow = gate*1024 + bn*32 + half*16 + (fr&15). Wave wc owns fi in [wc*4, wc*4+4).
// LDS: sA[128][64] + sB[128][64] bf16 = 32 KB. Proven swizzle: chunk k8 stored at
//   slot k8^(row&7) (via inverse-swizzled global src); read slot kc^(row&7).
__global__ void __launch_bounds__(256) lstm_g128(
    const u16* __restrict__ Abf, const u16* __restrict__ Wbf,
    const float* __restrict__ bix, const float* __restrict__ bfx,
    const float* __restrict__ bcx, const float* __restrict__ box_,
    const float* __restrict__ bih, const float* __restrict__ bfh,
    const float* __restrict__ bch, const float* __restrict__ boh,
    const float* __restrict__ cprev, float* __restrict__ out) {
  __shared__ alignas(16) u16 sA[8192];   // 16 KB: [128 rows][64 k]
  __shared__ alignas(16) u16 sB[8192];   // 16 KB: [128 fused rows][64 k]

  const u32 tid = threadIdx.x;
  const u32 lane = tid & 63u;
  const u32 wid = tid >> 6;
  const u32 wr = wid >> 1, wc = wid & 1u;
  const u32 l15 = lane & 15u, l4 = lane >> 4;
  const u32 r = lane >> 3, k8 = lane & 7u;
  const u32 col16 = k8 ^ r;                       // inverse-swizzled source chunk

  // bijective XCD swizzle: 4096 blocks, 8 XCDs, 512 per XCD.
  const u32 bidx = blockIdx.x;
  const u32 sid = (bidx & 7u) * 512u + (bidx >> 3);
  const u32 bm = sid >> 5, bn = sid & 31u;        // 128 x 32 tiles

  // staging source pointers (4 A-chunks + 4 B-chunks per thread)
  const u16* gAp[4];
  const u16* gBp[4];
  #pragma unroll
  for (int j = 0; j < 4; ++j) {
    // A: chunk c = (wid*4+j)*64 + lane; row = wid*32 + j*8 + r; col chunk = col16.
    gAp[j] = Abf + (size_t)(bm * 128u + wid * 32u + (u32)j * 8u + r) * KTOT + col16 * 8u;
    // B: q = wid*4+j; brow = q*8 + r; fi = q>>1; gate = fi&3; half = fi>>2 = wid>>1.
    u32 q = wid * 4u + (u32)j;
    u32 Wrow = ((q >> 1) & 3u) * 1024u + bn * 32u + (wid >> 1) * 16u + 8u * (q & 1u) + r;
    gBp[j] = Wbf + (size_t)Wrow * KTOT + col16 * 8u;
  }

#define STAGE(ktile) do { \
    _Pragma("unroll") \
    for (int j = 0; j < 4; ++j) { \
      gl_lds16(gAp[j] + (u32)(ktile) * 64u, sA + (wid * 4u + (u32)j) * 512u); \
      gl_lds16(gBp[j] + (u32)(ktile) * 64u, sB + (wid * 4u + (u32)j) * 512u); \
    } \
  } while (0)

  const char* cA = (const char*)sA;
  const char* cB = (const char*)sB;

  f32x4 acc[4][4];                                 // [gate][mf] = 64 regs
  #pragma unroll
  for (int g = 0; g < 4; ++g)
    #pragma unroll
    for (int m = 0; m < 4; ++m)
      acc[g][m] = (f32x4){0.f, 0.f, 0.f, 0.f};

  for (int kt = 0; kt < KTOT / 64; ++kt) {
    if (kt) __syncthreads();
    STAGE(kt);
    __syncthreads();

    #pragma unroll
    for (int s = 0; s < 2; ++s) {
      bf16x8 af[4];
      #pragma unroll
      for (int m = 0; m < 4; ++m) {
        u32 mrow = wr * 64u + (u32)m * 16u + l15;
        u32 off = mrow * 128u + (((u32)s * 64u + l4 * 16u) ^ ((mrow & 7u) << 4));
        af[m] = *(const bf16x8*)(cA + off);
      }
      #pragma unroll
      for (int g = 0; g < 4; ++g) {
        u32 frow = wc * 64u + (u32)g * 16u + l15;
        u32 off = frow * 128u + (((u32)s * 64u + l4 * 16u) ^ ((frow & 7u) << 4));
        bf16x8 bfr = *(const bf16x8*)(cB + off);
        #pragma unroll
        for (int m = 0; m < 4; ++m)
          acc[g][m] = __builtin_amdgcn_mfma_f32_16x16x32_bf16(af[m], bfr, acc[g][m], 0, 0, 0);
      }
    }
  }
#undef STAGE

  // ---- epilogue: gates -> (h_next, c_next) ----
  const u32 col = bn * 32u + wc * 16u + l15;
  const float bi = bix[col] + bih[col];
  const float bff = bfx[col] + bfh[col];
  const float bc = bcx[col] + bch[col];
  const float bo = box_[col] + boh[col];
  #pragma unroll
  for (int m = 0; m < 4; ++m) {
    u32 row0 = bm * 128u + wr * 64u + (u32)m * 16u + l4 * 4u;
    #pragma unroll
    for (int rr = 0; rr < 4; ++rr) {
      size_t idx = (size_t)(row0 + (u32)rr) * 1024 + col;
      float iv = acc[0][m][rr] + bi;
      float fv = acc[1][m][rr] + bff;
      float gv = tanh_fast(acc[2][m][rr] + bc);
      float ov = acc[3][m][rr] + bo;
      float cp = cprev[idx];
      float cn = gv * iv + cp * fv;
      out[idx] = ov * tanh_fast(cn);
      out[(size_t)16777216 + idx] = cn;
    }
  }
}

// ---- fallback (ws too small): round-1 reg-staged kernel, known correct ----
__global__ void __launch_bounds__(256, 2) lstm_gemm_fb(
    const float* __restrict__ x, const float* __restrict__ h,
    const float* __restrict__ wix, const float* __restrict__ wfx,
    const float* __restrict__ wcx, const float* __restrict__ wox,
    const float* __restrict__ wih, const float* __restrict__ wfh,
    const float* __restrict__ wch, const float* __restrict__ woh,
    const float* __restrict__ bix, const float* __restrict__ bfx,
    const float* __restrict__ bcx, const float* __restrict__ box_,
    const float* __restrict__ bih, const float* __restrict__ bfh,
    const float* __restrict__ bch, const float* __restrict__ boh,
    const float* __restrict__ cprev, float* __restrict__ out) {
  __shared__ alignas(16) u16 sA[128 * 64];
  __shared__ alignas(16) u16 sB[4 * 64 * 64];
  const u32 tid = threadIdx.x;
  const u32 lane = tid & 63u;
  const u32 wid = tid >> 6;
  const u32 wr = wid >> 1, wc = wid & 1u;
  const u32 bidx = blockIdx.x;
  const u32 bm = bidx >> 4, bn = bidx & 15u;
  f32x4 acc[4][4][2];
  #pragma unroll
  for (int g = 0; g < 4; ++g)
    #pragma unroll
    for (int m = 0; m < 4; ++m)
      #pragma unroll
      for (int n = 0; n < 2; ++n)
        acc[g][m][n] = (f32x4){0.f, 0.f, 0.f, 0.f};
  const u32 l15 = lane & 15u, l4 = lane >> 4;
  for (int kt = 0; kt < KTOT / 64; ++kt) {
    const u32 k0 = (u32)kt * 64u;
    if (kt) __syncthreads();
    #pragma unroll
    for (int c = 0; c < 4; ++c) {
      u32 chunk = tid + (u32)c * 256u;
      u32 row = chunk >> 3;
      u32 cp = (chunk & 7u) * 8u;
      u32 gk = k0 + cp;
      const float* src = (gk < 1024u) ? (x + (size_t)(bm * 128u + row) * 1024 + gk)
                                      : (h + (size_t)(bm * 128u + row) * 1024 + (gk - 1024u));
      float4 lo = *(const float4*)src;
      float4 hi = *(const float4*)(src + 4);
      u32 dst = row * 128u + ((cp * 2u) ^ ((row & 7u) << 4));
      *(bf16x8*)((char*)sA + dst) = pack8(lo, hi);
    }
    #pragma unroll
    for (int g = 0; g < 4; ++g) {
      const float* Wxg = (g == 0) ? wix : (g == 1) ? wfx : (g == 2) ? wcx : wox;
      const float* Whg = (g == 0) ? wih : (g == 1) ? wfh : (g == 2) ? wch : woh;
      #pragma unroll
      for (int cc = 0; cc < 2; ++cc) {
        u32 c3 = tid + (u32)cc * 256u;
        u32 row = c3 >> 3;
        u32 cp = (c3 & 7u) * 8u;
        u32 gk = k0 + cp;
        const float* src = (gk < 1024u) ? (Wxg + (size_t)(bn * 64u + row) * 1024 + gk)
                                        : (Whg + (size_t)(bn * 64u + row) * 1024 + (gk - 1024u));
        float4 lo = *(const float4*)src;
        float4 hi = *(const float4*)(src + 4);
        u32 dst = (u32)g * 8192u + row * 128u + ((cp * 2u) ^ ((row & 7u) << 4));
        *(bf16x8*)((char*)sB + dst) = pack8(lo, hi);
      }
    }
    __syncthreads();
    #pragma unroll
    for (int s = 0; s < 2; ++s) {
      bf16x8 af[4];
      #pragma unroll
      for (int m = 0; m < 4; ++m) {
        u32 mrow = wr * 64u + (u32)m * 16u + l15;
        u32 off = mrow * 128u + (((u32)s * 64u + l4 * 16u) ^ ((mrow & 7u) << 4));
        af[m] = *(const bf16x8*)((const char*)sA + off);
      }
      #pragma unroll
      for (int g = 0; g < 4; ++g) {
        #pragma unroll
        for (int nf = 0; nf < 2; ++nf) {
          u32 nrow = wc * 32u + (u32)nf * 16u + l15;
          u32 off = (u32)g * 8192u + nrow * 128u +
                    (((u32)s * 64u + l4 * 16u) ^ ((nrow & 7u) << 4));
          bf16x8 bfr = *(const bf16x8*)((const char*)sB + off);
          #pragma unroll
          for (int m = 0; m < 4; ++m)
            acc[g][m][nf] = __builtin_amdgcn_mfma_f32_16x16x32_bf16(af[m], bfr, acc[g][m][nf], 0, 0, 0);
        }
      }
    }
  }
  #pragma unroll
  for (int nf = 0; nf < 2; ++nf) {
    u32 col = bn * 64u + wc * 32u + (u32)nf * 16u + l15;
    float bi = bix[col] + bih[col];
    float bff = bfx[col] + bfh[col];
    float bc = bcx[col] + bch[col];
    float bo = box_[col] + boh[col];
    #pragma unroll
    for (int m = 0; m < 4; ++m) {
      u32 row0 = bm * 128u + wr * 64u + (u32)m * 16u + l4 * 4u;
      #pragma unroll
      for (int rr = 0; rr < 4; ++rr) {
        size_t idx = (size_t)(row0 + (u32)rr) * 1024 + col;
        float iv = acc[0][m][nf][rr] + bi;
        float fv = acc[1][m][nf][rr] + bff;
        float gv = tanh_fast(acc[2][m][nf][rr] + bc);
        float ov = acc[3][m][nf][rr] + bo;
        float cp = cprev[idx];
        float cn = gv * iv + cp * fv;
        out[idx] = ov * tanh_fast(cn);
        out[(size_t)16777216 + idx] = cn;
      }
    }
  }
}

extern "C" void kernel_launch(void* const* d_in, const int* in_sizes, int n_in,
                              void* d_out, int out_size, void* d_ws, size_t ws_size,
                              hipStream_t stream) {
  const float* x = (const float*)d_in[0];
  const float* h = (const float*)d_in[1];
  const float* cprev = (const float*)d_in[2];
  const float* wix = (const float*)d_in[3];  const float* bix = (const float*)d_in[4];
  const float* wfx = (const float*)d_in[5];  const float* bfx = (const float*)d_in[6];
  const float* wcx = (const float*)d_in[7];  const float* bcx = (const float*)d_in[8];
  const float* wox = (const float*)d_in[9];  const float* box_ = (const float*)d_in[10];
  const float* wih = (const float*)d_in[11]; const float* bih = (const float*)d_in[12];
  const float* wfh = (const float*)d_in[13]; const float* bfh = (const float*)d_in[14];
  const float* wch = (const float*)d_in[15]; const float* bch = (const float*)d_in[16];
  const float* woh = (const float*)d_in[17]; const float* boh = (const float*)d_in[18];
  float* out = (float*)d_out;

  const size_t needA = (size_t)MROWS * KTOT * 2;       // 64 MB
  const size_t needW = (size_t)4 * NCOLS * KTOT * 2;   // 16 MB

  if (ws_size >= needA + needW) {
    u16* Abf = (u16*)d_ws;
    u16* Wbf = (u16*)((char*)d_ws + needA);
    convAW<<<dim3(5120), dim3(256), 0, stream>>>(
        x, h, wix, wfx, wcx, wox, wih, wfh, wch, woh, Abf, Wbf);
    lstm_g128<<<dim3(4096), dim3(256), 0, stream>>>(
        Abf, Wbf, bix, bfx, bcx, box_, bih, bfh, bch, boh, cprev, out);
  } else {
    lstm_gemm_fb<<<dim3(2048), dim3(256), 0, stream>>>(
        x, h, wix, wfx, wcx, wox, wih, wfh, wch, woh,
        bix, bfx, bcx, box_, bih, bfh, bch, boh, cprev, out);
  }
}

// Round 9
// 348.237 us; speedup vs baseline: 1.0789x; 1.0789x over previous
//
#include <hip/hip_runtime.h>
#include <hip/hip_bf16.h>

// LSTM cell: B=16384, D=H=1024. out = (h_next, c_next) fp32, each 16384x1024.
// R9: R1's proven geometry/schedule (128M x 256fN tile, 2-barrier, 2 blocks/CU)
// with 32x32x16 MFMA (15% faster pipe, half the issue slots) + setprio.

#define MROWS 16384
#define NCOLS 1024
#define KTOT  2048

typedef __attribute__((ext_vector_type(8))) short bf16x8;
typedef __attribute__((ext_vector_type(16))) float f32x16;
typedef unsigned int u32;
typedef unsigned short u16;

__device__ __forceinline__ u16 f2bf(float f) {
  union { float f; u32 u; } v; v.f = f;
  u32 r = v.u + 0x7fffu + ((v.u >> 16) & 1u);   // RNE truncate f32->bf16
  return (u16)(r >> 16);
}

__device__ __forceinline__ bf16x8 pack8(float4 lo, float4 hi) {
  bf16x8 v;
  v[0] = (short)f2bf(lo.x); v[1] = (short)f2bf(lo.y);
  v[2] = (short)f2bf(lo.z); v[3] = (short)f2bf(lo.w);
  v[4] = (short)f2bf(hi.x); v[5] = (short)f2bf(hi.y);
  v[6] = (short)f2bf(hi.z); v[7] = (short)f2bf(hi.w);
  return v;
}

__device__ __forceinline__ float tanh_fast(float x) {
  float e = __expf(2.0f * x);
  return 1.0f - 2.0f / (e + 1.0f);
}

typedef __attribute__((address_space(1))) const u32 gas_u32;
typedef __attribute__((address_space(3))) u32 las_u32;

__device__ __forceinline__ void gl_lds16(const void* g, void* l) {
  __builtin_amdgcn_global_load_lds((gas_u32*)g, (las_u32*)l, 16, 0, 0);
}

// ---- merged conversion kernel (fast path) ----
// blocks 0..4095: A_bf16 [16384][2048] (cols 0..1023 = x, 1024..2047 = h)
// blocks 4096..5119: W_bf16 [gate][1024][2048], gate order i,f,c,o.
__global__ void __launch_bounds__(256) convAW(
    const float* __restrict__ x, const float* __restrict__ h,
    const float* __restrict__ wix, const float* __restrict__ wfx,
    const float* __restrict__ wcx, const float* __restrict__ wox,
    const float* __restrict__ wih, const float* __restrict__ wfh,
    const float* __restrict__ wch, const float* __restrict__ woh,
    u16* __restrict__ A, u16* __restrict__ W) {
  if (blockIdx.x < 4096u) {
    u32 t = blockIdx.x * 256u + threadIdx.x;
    #pragma unroll
    for (int i = 0; i < 4; ++i) {
      u32 chunk = t + (u32)i * 1048576u;
      u32 row = chunk >> 8;
      u32 cpos = (chunk & 255u) * 8u;
      const float* src = (cpos < 1024u) ? (x + (size_t)row * 1024 + cpos)
                                        : (h + (size_t)row * 1024 + (cpos - 1024u));
      float4 lo = *(const float4*)src;
      float4 hi = *(const float4*)(src + 4);
      *(bf16x8*)(A + (size_t)chunk * 8) = pack8(lo, hi);
    }
  } else {
    u32 t = (blockIdx.x - 4096u) * 256u + threadIdx.x;
    const float* WX[4] = {wix, wfx, wcx, wox};
    const float* WH[4] = {wih, wfh, wch, woh};
    #pragma unroll
    for (int g = 0; g < 4; ++g) {
      u32 n = t >> 8;
      u32 cpos = (t & 255u) * 8u;
      const float* src = (cpos < 1024u) ? (WX[g] + (size_t)n * 1024 + cpos)
                                        : (WH[g] + (size_t)n * 1024 + (cpos - 1024u));
      float4 lo = *(const float4*)src;
      float4 hi = *(const float4*)(src + 4);
      *(bf16x8*)(W + (size_t)g * 2097152 + (size_t)t * 8) = pack8(lo, hi);
    }
  }
}

// ---- fused 4-gate GEMM, 32x32x16 MFMA ----
// Block: 256 thr (4 waves 2x2). Tile 128(M) x 256 fused-N (4g x 64 cols), BK=64.
// Wave: 64M x 128fN = 2 M-tiles x 4 N-tiles(32) -> acc[4 g][2 mt] f32x16 = 128 regs.
// Fused B row fr in [0,256): gate=(fr>>5)&3, colblk=fr>>7, inner=fr&31;
//   Wrow = gate*1024 + bn*64 + colblk*32 + inner. Wave wc owns colblk==wc.
// LDS: sA[128][64] + sB[256][64] bf16 = 48 KB -> 2 blocks/CU (proven R1 regime).
// Swizzle (proven): 16B chunk k8 of row stored at slot k8^(row&7); src pre-swizzled.
__global__ void __launch_bounds__(256, 2) lstm_g32(
    const u16* __restrict__ Abf, const u16* __restrict__ Wbf,
    const float* __restrict__ bix, const float* __restrict__ bfx,
    const float* __restrict__ bcx, const float* __restrict__ box_,
    const float* __restrict__ bih, const float* __restrict__ bfh,
    const float* __restrict__ bch, const float* __restrict__ boh,
    const float* __restrict__ cprev, float* __restrict__ out) {
  __shared__ alignas(16) u16 sA[128 * 64];   // 16 KB
  __shared__ alignas(16) u16 sB[256 * 64];   // 32 KB

  const u32 tid = threadIdx.x;
  const u32 lane = tid & 63u;
  const u32 wid = tid >> 6;
  const u32 wr = wid >> 1, wc = wid & 1u;
  const u32 l31 = lane & 31u, l5 = lane >> 5;

  const u32 bidx = blockIdx.x;
  const u32 bm = bidx >> 4, bn = bidx & 15u;   // natural map: XCD k gets bn {k,k+8} -> W slice L2-resident

  // staging sources: A 1024 chunks (4/thr), B 2048 chunks (8/thr); inverse-swizzled.
  const u16* gAp[4];
  const u16* gBp[8];
  #pragma unroll
  for (int j = 0; j < 4; ++j) {
    u32 c = (wid * 4u + (u32)j) * 64u + lane;
    u32 row = c >> 3, k8 = c & 7u;
    gAp[j] = Abf + (size_t)(bm * 128u + row) * KTOT + (k8 ^ (row & 7u)) * 8u;
  }
  #pragma unroll
  for (int j = 0; j < 8; ++j) {
    u32 c = (wid * 8u + (u32)j) * 64u + lane;
    u32 fr = c >> 3, k8 = c & 7u;
    u32 Wrow = ((fr >> 5) & 3u) * 1024u + bn * 64u + (fr >> 7) * 32u + (fr & 31u);
    gBp[j] = Wbf + (size_t)Wrow * KTOT + (k8 ^ (fr & 7u)) * 8u;
  }

#define STAGE(ktile) do { \
    _Pragma("unroll") \
    for (int j = 0; j < 4; ++j) \
      gl_lds16(gAp[j] + (u32)(ktile) * 64u, sA + (wid * 4u + (u32)j) * 512u); \
    _Pragma("unroll") \
    for (int j = 0; j < 8; ++j) \
      gl_lds16(gBp[j] + (u32)(ktile) * 64u, sB + (wid * 8u + (u32)j) * 512u); \
  } while (0)

  const char* cA = (const char*)sA;
  const char* cB = (const char*)sB;

  f32x16 acc[4][2];                           // [gate][mt] = 128 regs
  #pragma unroll
  for (int g = 0; g < 4; ++g)
    #pragma unroll
    for (int mt = 0; mt < 2; ++mt)
      acc[g][mt] = (f32x16)(0.f);

  // loop-invariant read row bases
  const u32 mrow0 = wr * 64u + l31;           // + mt*32
  const u32 brow0 = wc * 128u + l31;          // + g*32

  for (int kt = 0; kt < KTOT / 64; ++kt) {
    STAGE(kt);
    __syncthreads();                           // drain stage + sync

    __builtin_amdgcn_s_setprio(1);
    #pragma unroll
    for (int ks = 0; ks < 4; ++ks) {
      const u32 kc = (u32)ks * 2u + l5;        // 16B chunk index within row
      bf16x8 a0, a1;
      {
        u32 r0 = mrow0;
        a0 = *(const bf16x8*)(cA + r0 * 128u + ((kc ^ (r0 & 7u)) << 4));
        u32 r1 = mrow0 + 32u;
        a1 = *(const bf16x8*)(cA + r1 * 128u + ((kc ^ (r1 & 7u)) << 4));
      }
      #pragma unroll
      for (int g = 0; g < 4; ++g) {
        u32 br = brow0 + (u32)g * 32u;
        bf16x8 bfr = *(const bf16x8*)(cB + br * 128u + ((kc ^ (br & 7u)) << 4));
        acc[g][0] = __builtin_amdgcn_mfma_f32_32x32x16_bf16(a0, bfr, acc[g][0], 0, 0, 0);
        acc[g][1] = __builtin_amdgcn_mfma_f32_32x32x16_bf16(a1, bfr, acc[g][1], 0, 0, 0);
      }
    }
    __builtin_amdgcn_s_setprio(0);
    __syncthreads();                           // buffer reuse guard
  }
#undef STAGE

  // ---- epilogue: gates -> (h_next, c_next) ----
  // C/D layout (m74/m101): col = lane&31, row = (reg&3) + 8*(reg>>2) + 4*(lane>>5).
  const u32 col = bn * 64u + wc * 32u + l31;
  const float bi = bix[col] + bih[col];
  const float bff = bfx[col] + bfh[col];
  const float bc = bcx[col] + bch[col];
  const float bo = box_[col] + boh[col];
  #pragma unroll
  for (int mt = 0; mt < 2; ++mt) {
    const u32 rbase = bm * 128u + wr * 64u + (u32)mt * 32u + 4u * l5;
    #pragma unroll
    for (int reg = 0; reg < 16; ++reg) {
      u32 row = rbase + (u32)(reg & 3) + 8u * (u32)(reg >> 2);
      size_t idx = (size_t)row * 1024 + col;
      float iv = acc[0][mt][reg] + bi;
      float fv = acc[1][mt][reg] + bff;
      float gv = tanh_fast(acc[2][mt][reg] + bc);
      float ov = acc[3][mt][reg] + bo;
      float cp = cprev[idx];
      float cn = gv * iv + cp * fv;
      out[idx] = ov * tanh_fast(cn);
      out[(size_t)16777216 + idx] = cn;
    }
  }
}

// ---- fallback (ws too small): round-1 reg-staged kernel, known correct ----
__global__ void __launch_bounds__(256, 2) lstm_gemm_fb(
    const float* __restrict__ x, const float* __restrict__ h,
    const float* __restrict__ wix, const float* __restrict__ wfx,
    const float* __restrict__ wcx, const float* __restrict__ wox,
    const float* __restrict__ wih, const float* __restrict__ wfh,
    const float* __restrict__ wch, const float* __restrict__ woh,
    const float* __restrict__ bix, const float* __restrict__ bfx,
    const float* __restrict__ bcx, const float* __restrict__ box_,
    const float* __restrict__ bih, const float* __restrict__ bfh,
    const float* __restrict__ bch, const float* __restrict__ boh,
    const float* __restrict__ cprev, float* __restrict__ out) {
  typedef __attribute__((ext_vector_type(4))) float f32x4;
  __shared__ alignas(16) u16 sA[128 * 64];
  __shared__ alignas(16) u16 sB[4 * 64 * 64];
  const u32 tid = threadIdx.x;
  const u32 lane = tid & 63u;
  const u32 wid = tid >> 6;
  const u32 wr = wid >> 1, wc = wid & 1u;
  const u32 bidx = blockIdx.x;
  const u32 bm = bidx >> 4, bn = bidx & 15u;
  f32x4 acc[4][4][2];
  #pragma unroll
  for (int g = 0; g < 4; ++g)
    #pragma unroll
    for (int m = 0; m < 4; ++m)
      #pragma unroll
      for (int n = 0; n < 2; ++n)
        acc[g][m][n] = (f32x4){0.f, 0.f, 0.f, 0.f};
  const u32 l15 = lane & 15u, l4 = lane >> 4;
  for (int kt = 0; kt < KTOT / 64; ++kt) {
    const u32 k0 = (u32)kt * 64u;
    if (kt) __syncthreads();
    #pragma unroll
    for (int c = 0; c < 4; ++c) {
      u32 chunk = tid + (u32)c * 256u;
      u32 row = chunk >> 3;
      u32 cp = (chunk & 7u) * 8u;
      u32 gk = k0 + cp;
      const float* src = (gk < 1024u) ? (x + (size_t)(bm * 128u + row) * 1024 + gk)
                                      : (h + (size_t)(bm * 128u + row) * 1024 + (gk - 1024u));
      float4 lo = *(const float4*)src;
      float4 hi = *(const float4*)(src + 4);
      u32 dst = row * 128u + ((cp * 2u) ^ ((row & 7u) << 4));
      *(bf16x8*)((char*)sA + dst) = pack8(lo, hi);
    }
    #pragma unroll
    for (int g = 0; g < 4; ++g) {
      const float* Wxg = (g == 0) ? wix : (g == 1) ? wfx : (g == 2) ? wcx : wox;
      const float* Whg = (g == 0) ? wih : (g == 1) ? wfh : (g == 2) ? wch : woh;
      #pragma unroll
      for (int cc = 0; cc < 2; ++cc) {
        u32 c3 = tid + (u32)cc * 256u;
        u32 row = c3 >> 3;
        u32 cp = (c3 & 7u) * 8u;
        u32 gk = k0 + cp;
        const float* src = (gk < 1024u) ? (Wxg + (size_t)(bn * 64u + row) * 1024 + gk)
                                        : (Whg + (size_t)(bn * 64u + row) * 1024 + (gk - 1024u));
        float4 lo = *(const float4*)src;
        float4 hi = *(const float4*)(src + 4);
        u32 dst = (u32)g * 8192u + row * 128u + ((cp * 2u) ^ ((row & 7u) << 4));
        *(bf16x8*)((char*)sB + dst) = pack8(lo, hi);
      }
    }
    __syncthreads();
    #pragma unroll
    for (int s = 0; s < 2; ++s) {
      bf16x8 af[4];
      #pragma unroll
      for (int m = 0; m < 4; ++m) {
        u32 mrow = wr * 64u + (u32)m * 16u + l15;
        u32 off = mrow * 128u + (((u32)s * 64u + l4 * 16u) ^ ((mrow & 7u) << 4));
        af[m] = *(const bf16x8*)((const char*)sA + off);
      }
      #pragma unroll
      for (int g = 0; g < 4; ++g) {
        #pragma unroll
        for (int nf = 0; nf < 2; ++nf) {
          u32 nrow = wc * 32u + (u32)nf * 16u + l15;
          u32 off = (u32)g * 8192u + nrow * 128u +
                    (((u32)s * 64u + l4 * 16u) ^ ((nrow & 7u) << 4));
          bf16x8 bfr = *(const bf16x8*)((const char*)sB + off);
          #pragma unroll
          for (int m = 0; m < 4; ++m)
            acc[g][m][nf] = __builtin_amdgcn_mfma_f32_16x16x32_bf16(af[m], bfr, acc[g][m][nf], 0, 0, 0);
        }
      }
    }
  }
  #pragma unroll
  for (int nf = 0; nf < 2; ++nf) {
    u32 col = bn * 64u + wc * 32u + (u32)nf * 16u + l15;
    float bi = bix[col] + bih[col];
    float bff = bfx[col] + bfh[col];
    float bc = bcx[col] + bch[col];
    float bo = box_[col] + boh[col];
    #pragma unroll
    for (int m = 0; m < 4; ++m) {
      u32 row0 = bm * 128u + wr * 64u + (u32)m * 16u + l4 * 4u;
      #pragma unroll
      for (int rr = 0; rr < 4; ++rr) {
        size_t idx = (size_t)(row0 + (u32)rr) * 1024 + col;
        float iv = acc[0][m][nf][rr] + bi;
        float fv = acc[1][m][nf][rr] + bff;
        float gv = tanh_fast(acc[2][m][nf][rr] + bc);
        float ov = acc[3][m][nf][rr] + bo;
        float cp = cprev[idx];
        float cn = gv * iv + cp * fv;
        out[idx] = ov * tanh_fast(cn);
        out[(size_t)16777216 + idx] = cn;
      }
    }
  }
}

extern "C" void kernel_launch(void* const* d_in, const int* in_sizes, int n_in,
                              void* d_out, int out_size, void* d_ws, size_t ws_size,
                              hipStream_t stream) {
  const float* x = (const float*)d_in[0];
  const float* h = (const float*)d_in[1];
  const float* cprev = (const float*)d_in[2];
  const float* wix = (const float*)d_in[3];  const float* bix = (const float*)d_in[4];
  const float* wfx = (const float*)d_in[5];  const float* bfx = (const float*)d_in[6];
  const float* wcx = (const float*)d_in[7];  const float* bcx = (const float*)d_in[8];
  const float* wox = (const float*)d_in[9];  const float* box_ = (const float*)d_in[10];
  const float* wih = (const float*)d_in[11]; const float* bih = (const float*)d_in[12];
  const float* wfh = (const float*)d_in[13]; const float* bfh = (const float*)d_in[14];
  const float* wch = (const float*)d_in[15]; const float* bch = (const float*)d_in[16];
  const float* woh = (const float*)d_in[17]; const float* boh = (const float*)d_in[18];
  float* out = (float*)d_out;

  const size_t needA = (size_t)MROWS * KTOT * 2;       // 64 MB
  const size_t needW = (size_t)4 * NCOLS * KTOT * 2;   // 16 MB

  if (ws_size >= needA + needW) {
    u16* Abf = (u16*)d_ws;
    u16* Wbf = (u16*)((char*)d_ws + needA);
    convAW<<<dim3(5120), dim3(256), 0, stream>>>(
        x, h, wix, wfx, wcx, wox, wih, wfh, wch, woh, Abf, Wbf);
    lstm_g32<<<dim3(2048), dim3(256), 0, stream>>>(
        Abf, Wbf, bix, bfx, bcx, box_, bih, bfh, bch, boh, cprev, out);
  } else {
    lstm_gemm_fb<<<dim3(2048), dim3(256), 0, stream>>>(
        x, h, wix, wfx, wcx, wox, wih, wfh, wch, woh,
        bix, bfx, bcx, box_, bih, bfh, bch, boh, cprev, out);
  }
}